// Round 6
// baseline (869.294 us; speedup 1.0000x reference)
//
#include <hip/hip_runtime.h>
#include <hip/hip_bf16.h>

typedef __attribute__((ext_vector_type(8))) __bf16 bf16x8;
typedef __attribute__((ext_vector_type(4))) float  f32x4;
typedef __attribute__((ext_vector_type(4))) int    i32x4;

#define SCOPE_AGENT __HIP_MEMORY_SCOPE_AGENT

static __device__ __forceinline__ f32x4 mfma16(bf16x8 a, bf16x8 b, f32x4 c) {
    return __builtin_amdgcn_mfma_f32_16x16x32_bf16(a, b, c, 0, 0, 0);
}
static __device__ __forceinline__ i32x4 mfma_i8(i32x4 a, i32x4 b, i32x4 c) {
    return __builtin_amdgcn_mfma_i32_16x16x64_i8(a, b, c, 0, 0, 0);
}
static __device__ __forceinline__ float sigm(float x)  { return 1.0f / (1.0f + __expf(-x)); }
static __device__ __forceinline__ float tanh_(float x) { return 1.0f - 2.0f / (__expf(2.0f * x) + 1.0f); }

static __device__ __forceinline__ bf16x8 cvt8(const float* __restrict__ p) {
    const float4* q = (const float4*)p;
    float4 a = q[0], b = q[1];
    bf16x8 r;
    r[0] = (__bf16)a.x; r[1] = (__bf16)a.y; r[2] = (__bf16)a.z; r[3] = (__bf16)a.w;
    r[4] = (__bf16)b.x; r[5] = (__bf16)b.y; r[6] = (__bf16)b.z; r[7] = (__bf16)b.w;
    return r;
}
static __device__ __forceinline__ void signal_add(unsigned int* p) {
    __hip_atomic_fetch_add(p, 1u, __ATOMIC_RELEASE, SCOPE_AGENT);
}
template <int SLP>
static __device__ __forceinline__ void wait_eq(unsigned int* p, unsigned int v) {
    while (__hip_atomic_load(p, __ATOMIC_RELAXED, SCOPE_AGENT) != v)
        __builtin_amdgcn_s_sleep(SLP);
    (void)__hip_atomic_load(p, __ATOMIC_ACQUIRE, SCOPE_AGENT);
}
union g4u { unsigned long long q; __bf16 h[4]; };

// ---------------------------------------------------------------------------
// ws layout (bytes):
//   0        flags (1024, zeroed):
//            Gx blk flags @ u32[(l*2+dir)*4 + nt]  (==8 when PA block done)
//            z flags      @ u32[48+l]              (==2 when both dirs done)
//            whh per-dl   @ u32[60+dl]             (==128 when dl quantized)
//   1024     zbuf  [2][64][512] bf16 = 131072   (zbuf0 survives -> fc)
//   132096   Gx_g  [2][64][1024] bf16 = 262144  (dead after lstm)
//   66560    convWb overlay (554688) over zbuf1+Gx — written during the FC
//            dispatch (after lstm), read by convs/head. No race.
//   621248   arenaA (20,574,208): x4b / c3o / c2o / c1o / c0o
//   21195456 arenaB: p3/p2/p1/p0 @0; fcWb @2,097,152 (dead before p1);
//            WhhQ i8 @11,534,336 + swp @14,155,776 (dead after lstm)
// NOTE (round-5 lesson): persistent multi-phase kernels where the MAJORITY of
// blocks spin-gate on earlier phases deadlock — workgroup dispatch order is
// UNDEFINED across XCDs; residency can fill with spinners. Spinner count must
// stay << resident capacity (here: 2 recurrence blocks only).
// ---------------------------------------------------------------------------
#define ZBUF_OFF   1024
#define GX_OFF     132096
#define CONVW_OFF  66560
#define ARENA_A    621248
#define ARENA_B    21195456
#define WHHQ_BOFF  11534336
#define SWP_BOFF   14155776

#define NB_LSTM 18
#define NB_WHH  1280
#define NB_FCW  640

// ---------------------------------------------------------------------------
// Fused LSTM + weight-precvt, grid = 1938 x 512:
//  bid 0..15 : Phase-A WGs (dir=bid>>3, sub=bid&7): Gx = Wih@x + b, produced in
//    four 16-timestep blocks in consumer order, signalled per block.
//  bid 16,17 : recurrence WGs (dir=bid-16), one CU each (MFMA i8 matvec,
//    wf[8][4] in AGPRs). Gx staged per 16-step block to LDS (32 KB bulk).
//    z written straight to global per step.
//    Layer l gates ONLY on its own dl's 128 precvt blocks (flags[60+dl]) —
//    the all-1280 wait was ~+60us on the recurrence critical path. Deadlock-
//    free for ANY dispatch order: precvt blocks wait on nothing.
//  bid 18..1297   : precvt_whh (Whh -> int8 A-fragments + scales), per-dl
//    signalled (128 blocks per dl, dl = (bid-18)/128).
//  bid 1298..1937 : fcW f32->bf16 (independent; consumed after lstm).
// m = cell*4 + gate everywhere; weight row r = gate*256 + cell.
// ---------------------------------------------------------------------------
__global__ __launch_bounds__(512) __attribute__((amdgpu_waves_per_eu(2, 2)))
void lstm_fused(
    const float* __restrict__ audio,
    const float* __restrict__ Wih0,     // [2][1024][768] f32
    const float* __restrict__ WihL,     // [4][2][1024][512] f32
    const float* __restrict__ Whh0, const float* __restrict__ WhhL,
    signed char* __restrict__ WhhQ, float* __restrict__ swp,
    const float* __restrict__ b0, const float* __restrict__ bL,
    const float* __restrict__ fcW, __bf16* __restrict__ fcWb,
    unsigned short* __restrict__ Gx_g,  // [2][64][1024] bf16 bits
    unsigned int* __restrict__ flags,
    unsigned short* __restrict__ zbuf)  // [2][64][512] bf16 bits
{
    const int bid = blockIdx.x;
    const int tid = threadIdx.x;
    const int wave = tid >> 6, lane = tid & 63, ln = lane & 15, quad = lane >> 4;

    __shared__ __align__(16) signed char    hq[2][256];
    __shared__ __align__(16) unsigned short gx_l[16384];   // [16 t][1024] bf16 bits

    if (bid >= NB_LSTM) {
        if (bid < NB_LSTM + NB_WHH) {
            // ---------------- precvt_whh (per-dl signalled) ----------------
            const int g  = (bid - NB_LSTM) * 8 + wave;   // 0..10239
            const int dl = g >> 10;
            const int r  = g & 1023;
            const float* src = (dl < 2 ? Whh0 + (size_t)dl * 262144
                                       : WhhL + (size_t)(dl - 2) * 262144) + (size_t)r * 256;
            float4 v = *(const float4*)(src + lane * 4);
            float am = fmaxf(fmaxf(fabsf(v.x), fabsf(v.y)), fmaxf(fabsf(v.z), fabsf(v.w)));
            #pragma unroll
            for (int m = 1; m < 64; m <<= 1) am = fmaxf(am, __shfl_xor(am, m));
            const float inv = am > 0.f ? 127.f / am : 0.f;
            int q0 = __float2int_rn(v.x * inv), q1 = __float2int_rn(v.y * inv);
            int q2 = __float2int_rn(v.z * inv), q3 = __float2int_rn(v.w * inv);
            unsigned pk = (q0 & 255) | ((q1 & 255) << 8) | ((q2 & 255) << 16) | ((q3 & 255) << 24);
            const int gate = r >> 8, cell = r & 255;
            const int m  = cell * 4 + gate;
            const int lm = m & 15, mt = m >> 4;
            const int k  = lane * 4;
            const int kc = k >> 6, qd = (k >> 4) & 3, j = k & 15;
            size_t addr = ((((size_t)dl * 64 + mt) * 4 + kc) * 64 + (qd * 16 + lm)) * 16 + j;
            *(unsigned*)(WhhQ + addr) = pk;
            if (lane == 0) swp[(size_t)dl * 1024 + cell * 4 + gate] = am / 127.f;
            __syncthreads();
            const int dlb = ((bid - NB_LSTM) * 8) >> 10;   // block-uniform dl
            if (tid == 0) { __threadfence(); signal_add(&flags[60 + dlb]); }
        } else {
            // ---------------- fcW f32 -> bf16 ----------------
            int f = ((bid - NB_LSTM - NB_WHH) * 512 + tid) * 4;
            if (f < 1310720) {
                float4 v = *(const float4*)(fcW + f);
                g4u u;
                u.h[0] = (__bf16)v.x; u.h[1] = (__bf16)v.y;
                u.h[2] = (__bf16)v.z; u.h[3] = (__bf16)v.w;
                *(unsigned long long*)(fcWb + f) = u.q;
            }
        }
        return;
    }

    if (bid < 16) {
        // ---------------- Phase A ----------------
        const int dir = bid >> 3, sub = bid & 7;
        const int gmt = sub * 8 + wave;          // global m-tile 0..63
        const int m_a = gmt * 16 + ln;
        const int r_a = (m_a & 3) * 256 + (m_a >> 2);
        unsigned short* GxO = Gx_g + (size_t)dir * 65536;

        // ---- layer 0 (no wait; weights cached in regs) ----
        {
            const float* Wih_l = Wih0 + (size_t)dir * 786432;
            const float* b_l   = b0 + (size_t)dir * 1024;
            bf16x8 afr[24];
            #pragma unroll
            for (int kc = 0; kc < 24; ++kc)
                afr[kc] = cvt8(Wih_l + (size_t)r_a * 768 + kc * 32 + quad * 8);
            float bv[4];
            #pragma unroll
            for (int reg = 0; reg < 4; ++reg) {
                const int m_row = gmt * 16 + quad * 4 + reg;
                bv[reg] = b_l[(m_row & 3) * 256 + (m_row >> 2)];
            }
            for (int ii = 0; ii < 4; ++ii) {
                const int nt = dir ? 3 - ii : ii;
                const int t  = nt * 16 + ln;
                f32x4 acA = (f32x4){0.f, 0.f, 0.f, 0.f};
                f32x4 acB = (f32x4){0.f, 0.f, 0.f, 0.f};
                #pragma unroll
                for (int kc = 0; kc < 24; kc += 2) {
                    acA = mfma16(afr[kc],
                                 cvt8(audio + (size_t)t * 768 + kc * 32 + quad * 8), acA);
                    acB = mfma16(afr[kc + 1],
                                 cvt8(audio + (size_t)t * 768 + (kc + 1) * 32 + quad * 8), acB);
                }
                f32x4 acc = acA + acB;
                #pragma unroll
                for (int reg = 0; reg < 4; ++reg) {
                    const int m_row = gmt * 16 + quad * 4 + reg;
                    __bf16 v = (__bf16)(acc[reg] + bv[reg]);
                    GxO[(size_t)t * 1024 + m_row] = __builtin_bit_cast(unsigned short, v);
                }
                __syncthreads();
                if (tid == 0) { __threadfence(); signal_add(&flags[(0 * 2 + dir) * 4 + nt]); }
            }
        }

        // ---- layers 1-4: prefetch Wih fragment into regs, THEN wait ----
        for (int l = 1; l < 5; ++l) {
            const float* Wih_l = WihL + (size_t)((l - 1) * 2 + dir) * 524288;
            const float* b_l   = bL + (size_t)((l - 1) * 2 + dir) * 1024;
            bf16x8 afr[16];
            #pragma unroll
            for (int kc = 0; kc < 16; ++kc)
                afr[kc] = cvt8(Wih_l + (size_t)r_a * 512 + kc * 32 + quad * 8);
            float bv[4];
            #pragma unroll
            for (int reg = 0; reg < 4; ++reg) {
                const int m_row = gmt * 16 + quad * 4 + reg;
                bv[reg] = b_l[(m_row & 3) * 256 + (m_row >> 2)];
            }
            if (tid == 0) wait_eq<4>(&flags[48 + (l - 1)], 2u);
            __syncthreads();
            const __bf16* zp = (const __bf16*)(zbuf + (size_t)((l - 1) & 1) * 32768);

            for (int ii = 0; ii < 4; ++ii) {
                const int nt = dir ? 3 - ii : ii;
                const int t  = nt * 16 + ln;
                f32x4 acA = (f32x4){0.f, 0.f, 0.f, 0.f};
                f32x4 acB = (f32x4){0.f, 0.f, 0.f, 0.f};
                #pragma unroll
                for (int kc = 0; kc < 16; kc += 2) {
                    acA = mfma16(afr[kc],
                                 *(const bf16x8*)(zp + (size_t)t * 512 + kc * 32 + quad * 8), acA);
                    acB = mfma16(afr[kc + 1],
                                 *(const bf16x8*)(zp + (size_t)t * 512 + (kc + 1) * 32 + quad * 8), acB);
                }
                f32x4 acc = acA + acB;
                #pragma unroll
                for (int reg = 0; reg < 4; ++reg) {
                    const int m_row = gmt * 16 + quad * 4 + reg;
                    __bf16 v = (__bf16)(acc[reg] + bv[reg]);
                    GxO[(size_t)t * 1024 + m_row] = __builtin_bit_cast(unsigned short, v);
                }
                __syncthreads();
                if (tid == 0) { __threadfence(); signal_add(&flags[(l * 2 + dir) * 4 + nt]); }
            }
        }
    } else {
        // ---------------- recurrence (MFMA i8, LDS-staged Gx) ----------------
        const int dir = bid - 16;
        const unsigned short* Gx_d = Gx_g + (size_t)dir * 65536;
        const bool owner = (ln < 8);
        const int cell = wave * 32 + ln * 4 + quad;   // valid when owner
        const int gcell = owner ? cell : 0;
        const i32x4 czero = (i32x4){0, 0, 0, 0};

        for (int l = 0; l < 5; ++l) {
            const int dl = l * 2 + dir;
            // gate only on THIS layer's 128 weight blocks
            if (tid == 0) wait_eq<4>(&flags[60 + dl], 128u);
            __syncthreads();
            // register-resident int8 Whh (loads overlap the Phase-A wait)
            i32x4 wf[8][4];
            const i32x4* wb = (const i32x4*)(WhhQ + (size_t)dl * 262144);
            #pragma unroll
            for (int i = 0; i < 8; ++i)
                #pragma unroll
                for (int kc = 0; kc < 4; ++kc)
                    wf[i][kc] = wb[(size_t)(((wave * 8 + i) * 4 + kc)) * 64 + lane];
            float sc0 = 0.f, sc1 = 0.f, sc2 = 0.f, sc3 = 0.f;
            if (owner) {
                float4 s4 = *(const float4*)(swp + (size_t)dl * 1024 + cell * 4);
                const float f = 1.f / 127.f;
                sc0 = s4.x * f; sc1 = s4.y * f; sc2 = s4.z * f; sc3 = s4.w * f;
            }
            if (tid < 64) ((unsigned int*)hq[0])[tid] = 0;
            float cst = 0.f;
            unsigned short* zl = zbuf + (size_t)(l & 1) * 32768;
            const int gxbase = (l * 2 + dir) * 4;

            for (int s = 0; s < 64; ++s) {
                if ((s & 15) == 0) {
                    // wait for + stage the next 16-t block of Gx (32 KB)
                    const int nt = dir ? 3 - (s >> 4) : (s >> 4);
                    if (tid == 0) wait_eq<1>(&flags[gxbase + nt], 8u);
                    __syncthreads();
                    const float4* src = (const float4*)(Gx_d + (size_t)nt * 16384);
                    float4* dst = (float4*)gx_l;
                    #pragma unroll
                    for (int i = 0; i < 4; ++i) dst[i * 512 + tid] = src[i * 512 + tid];
                    __syncthreads();
                }
                const int t = dir ? (63 - s) : s;
                const int tl = t & 15;
                const int cur = s & 1, nxt = cur ^ 1;
                // early, unconditional LDS read of this step's gate bias
                g4u gx;
                gx.q = *(const unsigned long long*)&gx_l[tl * 1024 + gcell * 4];
                i32x4 acc[8];
                {
                    i32x4 b0v = *(const i32x4*)&hq[cur][quad * 16];
                    #pragma unroll
                    for (int i = 0; i < 8; ++i) acc[i] = mfma_i8(wf[i][0], b0v, czero);
                }
                #pragma unroll
                for (int kc = 1; kc < 4; ++kc) {
                    i32x4 b = *(const i32x4*)&hq[cur][kc * 64 + quad * 16];
                    #pragma unroll
                    for (int i = 0; i < 8; ++i) acc[i] = mfma_i8(wf[i][kc], b, acc[i]);
                }
                i32x4 a = acc[0];
                #pragma unroll
                for (int j = 1; j < 8; ++j) if (ln == j) a = acc[j];
                if (owner) {
                    float gi = (float)a[0] * sc0 + (float)gx.h[0];
                    float gf = (float)a[1] * sc1 + (float)gx.h[1];
                    float gg = (float)a[2] * sc2 + (float)gx.h[2];
                    float go = (float)a[3] * sc3 + (float)gx.h[3];
                    cst = sigm(gf) * cst + sigm(gi) * tanh_(gg);
                    float h = sigm(go) * tanh_(cst);
                    int q = __float2int_rn(h * 127.f);
                    hq[nxt][cell] = (signed char)q;
                    __bf16 zv = (__bf16)((float)q * (1.f / 127.f));
                    zl[(size_t)t * 512 + dir * 256 + cell] =
                        __builtin_bit_cast(unsigned short, zv);
                }
                __syncthreads();
            }
            // all z stores drained by the last step's barrier; publish layer
            if (tid == 0) { __threadfence(); signal_add(&flags[48 + l]); }
        }
    }
}

// ---------------------------------------------------------------------------
// fc (+ conv-weight conversion in spare blocks; runs after lstm so the
// zbuf1/Gx overlay region is dead): grid = 40 + 271.
// ---------------------------------------------------------------------------
__global__ __launch_bounds__(256) void fc_kernel(
    const __bf16* __restrict__ zb, const __bf16* __restrict__ W,
    const float* __restrict__ bb, __bf16* __restrict__ out,
    const float* __restrict__ c3W, const float* __restrict__ c2W,
    const float* __restrict__ c1W, const float* __restrict__ c0W,
    const float* __restrict__ hW, __bf16* __restrict__ convWb)
{
    const int tid = threadIdx.x;
    if (blockIdx.x >= 40) {
        int f = ((blockIdx.x - 40) * 256 + tid) * 4;
        if (f < 277344) {
            const float* src; int off;
            if (f < 147456)      { src = c3W; off = f; }
            else if (f < 221184) { src = c2W; off = f - 147456; }
            else if (f < 258048) { src = c1W; off = f - 221184; }
            else if (f < 276480) { src = c0W; off = f - 258048; }
            else                 { src = hW;  off = f - 276480; }
            float4 v = *(const float4*)(src + off);
            g4u u;
            u.h[0] = (__bf16)v.x; u.h[1] = (__bf16)v.y;
            u.h[2] = (__bf16)v.z; u.h[3] = (__bf16)v.w;
            *(unsigned long long*)(convWb + f) = u.q;
        }
        return;
    }
    const int wave = tid >> 6, lane = tid & 63, ln = lane & 15, quad = lane >> 4;
    const int nbase = blockIdx.x * 64;
    f32x4 acc[4];
    #pragma unroll
    for (int nt = 0; nt < 4; nt++) acc[nt] = (f32x4){0.f, 0.f, 0.f, 0.f};
    #pragma unroll 2
    for (int kc = 0; kc < 16; kc++) {
        const int k0 = kc * 32 + quad * 8;
        bf16x8 a = *(const bf16x8*)(zb + (size_t)(wave * 16 + ln) * 512 + k0);
        #pragma unroll
        for (int nt = 0; nt < 4; nt++) {
            bf16x8 b = *(const bf16x8*)(W + (size_t)(nbase + nt * 16 + ln) * 512 + k0);
            acc[nt] = mfma16(a, b, acc[nt]);
        }
    }
    #pragma unroll
    for (int nt = 0; nt < 4; nt++) {
        const int n = nbase + nt * 16 + ln;
        const float bv = bb[n];
        #pragma unroll
        for (int reg = 0; reg < 4; reg++) {
            const int t = wave * 16 + quad * 4 + reg;
            out[(size_t)((n >> 7) * 64 + t) * 128 + (n & 127)] = (__bf16)(acc[nt][reg] + bv);
        }
    }
}

// ---------------------------------------------------------------------------
// pool: out[r][t][:] = sum_{s=0..2} vals[3r+s] * in[cols[3r+s]][t][:]
// ---------------------------------------------------------------------------
template <int C>
__global__ __launch_bounds__(256) void pool_kernel(
    const __bf16* __restrict__ in, __bf16* __restrict__ out,
    const int* __restrict__ cols, const float* __restrict__ vals, int V)
{
    const int P = 64 * C / 8;
    const int gid = blockIdx.x * 256 + threadIdx.x;
    if (gid >= V * P) return;
    const int r = gid / P;
    const int rem = gid - r * P;
    float acc[8] = {0.f, 0.f, 0.f, 0.f, 0.f, 0.f, 0.f, 0.f};
    #pragma unroll
    for (int s = 0; s < 3; s++) {
        const int col = cols[3 * r + s];
        const float vv = vals[3 * r + s];
        bf16x8 x = *(const bf16x8*)(in + (size_t)col * 64 * C + rem * 8);
        #pragma unroll
        for (int e = 0; e < 8; e++) acc[e] += vv * (float)x[e];
    }
    bf16x8 ov;
    #pragma unroll
    for (int e = 0; e < 8; e++) ov[e] = (__bf16)acc[e];
    *(bf16x8*)(out + (size_t)r * 64 * C + rem * 8) = ov;
}

// ---------------------------------------------------------------------------
// spiral conv + ELU: one WAVE per (vertex, 16-t chunk). grid = (V, 4) x 64.
// ---------------------------------------------------------------------------
template <int CIN, int COUT>
__global__ __launch_bounds__(64) void conv_kernel(
    const __bf16* __restrict__ in, __bf16* __restrict__ out,
    const int* __restrict__ idx, const __bf16* __restrict__ W,
    const float* __restrict__ bias)
{
    constexpr int K = 9 * CIN;
    constexpr int NT = COUT / 16;
    constexpr int NKC = K / 32;
    const int v = blockIdx.x;
    const int lane = threadIdx.x, ln = lane & 15, quad = lane >> 4;
    const int t0 = blockIdx.y * 16;
    __shared__ int sIdx[9];
    if (lane < 9) sIdx[lane] = idx[v * 9 + lane];
    __syncthreads();
    f32x4 acc[NT];
    #pragma unroll
    for (int nt = 0; nt < NT; nt++) acc[nt] = (f32x4){0.f, 0.f, 0.f, 0.f};
    const int tt = t0 + ln;
    for (int kc = 0; kc < NKC; kc++) {
        const int k0 = kc * 32;
        const int l = k0 / CIN;
        const int c = (k0 & (CIN - 1)) + quad * 8;
        const int row = sIdx[l];
        bf16x8 a = *(const bf16x8*)(in + ((size_t)row * 64 + tt) * CIN + c);
        #pragma unroll
        for (int nt = 0; nt < NT; nt++) {
            bf16x8 b = *(const bf16x8*)(W + (size_t)(nt * 16 + ln) * K + k0 + quad * 8);
            acc[nt] = mfma16(a, b, acc[nt]);
        }
    }
    #pragma unroll
    for (int nt = 0; nt < NT; nt++) {
        const int n = nt * 16 + ln;
        const float bv = bias[n];
        #pragma unroll
        for (int reg = 0; reg < 4; reg++) {
            const int t = t0 + quad * 4 + reg;
            float val = acc[nt][reg] + bv;
            val = val > 0.f ? val : (__expf(val) - 1.f);   // ELU
            out[((size_t)v * 64 + t) * COUT + n] = (__bf16)val;
        }
    }
}

// ---------------------------------------------------------------------------
// head: spiral conv to 3 ch + actor offset -> [64][5023][3] f32.
// One wave per (vertex, 16-t chunk): grid = (5023, 4) x 64.
// ---------------------------------------------------------------------------
__global__ __launch_bounds__(64) void head_kernel(
    const __bf16* __restrict__ in, float* __restrict__ out,
    const int* __restrict__ idx, const __bf16* __restrict__ W,
    const float* __restrict__ bias, const float* __restrict__ actor)
{
    const int v = blockIdx.x;
    const int lane = threadIdx.x, ln = lane & 15, quad = lane >> 4;
    const int t0 = blockIdx.y * 16;
    __shared__ int sIdx[9];
    if (lane < 9) sIdx[lane] = idx[v * 9 + lane];
    __syncthreads();
    f32x4 acc = (f32x4){0.f, 0.f, 0.f, 0.f};
    const int tt = t0 + ln;
    const int rown = ln < 3 ? ln : 0;
    #pragma unroll
    for (int kc = 0; kc < 9; kc++) {
        const int row = sIdx[kc];
        bf16x8 a = *(const bf16x8*)(in + ((size_t)row * 64 + tt) * 32 + quad * 8);
        bf16x8 b = *(const bf16x8*)(W + (size_t)rown * 288 + kc * 32 + quad * 8);
        acc = mfma16(a, b, acc);
    }
    if (ln < 3) {
        const float bv = bias[ln];
        const float av = actor[v * 3 + ln];
        #pragma unroll
        for (int reg = 0; reg < 4; reg++) {
            const int t = t0 + quad * 4 + reg;
            out[((size_t)t * 5023 + v) * 3 + ln] = acc[reg] + bv + av;
        }
    }
}

extern "C" void kernel_launch(void* const* d_in, const int* in_sizes, int n_in,
                              void* d_out, int out_size, void* d_ws, size_t ws_size,
                              hipStream_t stream) {
    const float* audio = (const float*)d_in[0];
    const float* actor = (const float*)d_in[1];
    const float* Wih0  = (const float*)d_in[2];
    const float* Whh0  = (const float*)d_in[3];
    const float* b0    = (const float*)d_in[4];
    const float* WihL  = (const float*)d_in[5];
    const float* WhhL  = (const float*)d_in[6];
    const float* bLs   = (const float*)d_in[7];
    const float* fcW   = (const float*)d_in[8];
    const float* fcb   = (const float*)d_in[9];
    const float* c3W = (const float*)d_in[10]; const float* c3b = (const float*)d_in[11];
    const float* c2W = (const float*)d_in[12]; const float* c2b = (const float*)d_in[13];
    const float* c1W = (const float*)d_in[14]; const float* c1b = (const float*)d_in[15];
    const float* c0W = (const float*)d_in[16]; const float* c0b = (const float*)d_in[17];
    const float* hW  = (const float*)d_in[18]; const float* hb  = (const float*)d_in[19];
    const int* idx0 = (const int*)d_in[20];
    const int* idx1 = (const int*)d_in[21];
    const int* idx2 = (const int*)d_in[22];
    const int* idx3 = (const int*)d_in[23];
    const int* cols0 = (const int*)d_in[25]; const float* vals0 = (const float*)d_in[26];
    const int* cols1 = (const int*)d_in[28]; const float* vals1 = (const float*)d_in[29];
    const int* cols2 = (const int*)d_in[31]; const float* vals2 = (const float*)d_in[32];
    const int* cols3 = (const int*)d_in[34]; const float* vals3 = (const float*)d_in[35];

    char* ws = (char*)d_ws;
    unsigned int*   flags = (unsigned int*)ws;
    unsigned short* zbuf  = (unsigned short*)(ws + ZBUF_OFF);
    unsigned short* GxG   = (unsigned short*)(ws + GX_OFF);
    __bf16*         convWb = (__bf16*)(ws + CONVW_OFF);
    char* arenaA = ws + ARENA_A;
    char* arenaB = ws + ARENA_B;

    signed char* whhq = (signed char*)(arenaB + WHHQ_BOFF);   // dead after lstm
    float*       swp  = (float*)(arenaB + SWP_BOFF);          // dead after lstm
    __bf16*      fcWb = (__bf16*)(arenaB + 2097152);          // dead after fc

    __bf16* x4b = (__bf16*)arenaA;   // [20][64][128]
    __bf16* p3  = (__bf16*)arenaB;   // [79][64][128]
    __bf16* c3o = (__bf16*)arenaA;   // [79][64][128]
    __bf16* p2  = (__bf16*)arenaB;   // [314][64][128]
    __bf16* c2o = (__bf16*)arenaA;   // [314][64][64]
    __bf16* p1  = (__bf16*)arenaB;   // [1256][64][64]
    __bf16* c1o = (__bf16*)arenaA;   // [1256][64][64]
    __bf16* p0  = (__bf16*)arenaB;   // [5023][64][64]
    __bf16* c0o = (__bf16*)arenaA;   // [5023][64][32]

    (void)hipMemsetAsync(ws, 0, 1024, stream);   // flags

    lstm_fused<<<NB_LSTM + NB_WHH + NB_FCW, 512, 0, stream>>>(
        audio, Wih0, WihL, Whh0, WhhL, whhq, swp, b0, bLs,
        fcW, fcWb, GxG, flags, zbuf);

    fc_kernel<<<40 + 271, 256, 0, stream>>>((const __bf16*)zbuf, fcWb, fcb, x4b,
                                            c3W, c2W, c1W, c0W, hW, convWb);

    { int n = 79 * 64 * 128 / 8;
      pool_kernel<128><<<(n + 255) / 256, 256, 0, stream>>>(x4b, p3, cols3, vals3, 79);
      conv_kernel<128, 128><<<dim3(79, 4), 64, 0, stream>>>(p3, c3o, idx3, convWb + 0, c3b); }
    { int n = 314 * 64 * 128 / 8;
      pool_kernel<128><<<(n + 255) / 256, 256, 0, stream>>>(c3o, p2, cols2, vals2, 314);
      conv_kernel<128, 64><<<dim3(314, 4), 64, 0, stream>>>(p2, c2o, idx2, convWb + 147456, c2b); }
    { int n = 1256 * 64 * 64 / 8;
      pool_kernel<64><<<(n + 255) / 256, 256, 0, stream>>>(c2o, p1, cols1, vals1, 1256);
      conv_kernel<64, 64><<<dim3(1256, 4), 64, 0, stream>>>(p1, c1o, idx1, convWb + 221184, c1b); }
    { int n = 5023 * 64 * 64 / 8;
      pool_kernel<64><<<(n + 255) / 256, 256, 0, stream>>>(c1o, p0, cols0, vals0, 5023);
      conv_kernel<64, 32><<<dim3(5023, 4), 64, 0, stream>>>(p0, c0o, idx0, convWb + 258048, c0b); }

    head_kernel<<<dim3(5023, 4), 64, 0, stream>>>(c0o, (float*)d_out, idx0,
                                                  convWb + 276480, hb, actor);
}

// Round 7
// 816.310 us; speedup vs baseline: 1.0649x; 1.0649x over previous
//
#include <hip/hip_runtime.h>
#include <hip/hip_bf16.h>

typedef __attribute__((ext_vector_type(8))) __bf16 bf16x8;
typedef __attribute__((ext_vector_type(4))) float  f32x4;
typedef __attribute__((ext_vector_type(4))) int    i32x4;

#define SCOPE_AGENT __HIP_MEMORY_SCOPE_AGENT

static __device__ __forceinline__ f32x4 mfma16(bf16x8 a, bf16x8 b, f32x4 c) {
    return __builtin_amdgcn_mfma_f32_16x16x32_bf16(a, b, c, 0, 0, 0);
}
static __device__ __forceinline__ i32x4 mfma_i8(i32x4 a, i32x4 b, i32x4 c) {
    return __builtin_amdgcn_mfma_i32_16x16x64_i8(a, b, c, 0, 0, 0);
}
static __device__ __forceinline__ float sigm(float x)  { return 1.0f / (1.0f + __expf(-x)); }
static __device__ __forceinline__ float tanh_(float x) { return 1.0f - 2.0f / (__expf(2.0f * x) + 1.0f); }

static __device__ __forceinline__ bf16x8 cvt8(const float* __restrict__ p) {
    const float4* q = (const float4*)p;
    float4 a = q[0], b = q[1];
    bf16x8 r;
    r[0] = (__bf16)a.x; r[1] = (__bf16)a.y; r[2] = (__bf16)a.z; r[3] = (__bf16)a.w;
    r[4] = (__bf16)b.x; r[5] = (__bf16)b.y; r[6] = (__bf16)b.z; r[7] = (__bf16)b.w;
    return r;
}
static __device__ __forceinline__ void signal_add(unsigned int* p) {
    __hip_atomic_fetch_add(p, 1u, __ATOMIC_RELEASE, SCOPE_AGENT);
}
template <int SLP>
static __device__ __forceinline__ void wait_eq(unsigned int* p, unsigned int v) {
    while (__hip_atomic_load(p, __ATOMIC_RELAXED, SCOPE_AGENT) != v)
        __builtin_amdgcn_s_sleep(SLP);
    (void)__hip_atomic_load(p, __ATOMIC_ACQUIRE, SCOPE_AGENT);
}
union g4u { unsigned long long q; __bf16 h[4]; };

// ---------------------------------------------------------------------------
// ws layout (bytes):
//   0        flags (1024, zeroed):
//            Gx blk flags @ u32[(l*2+dir)*4 + nt]  (==8 when PA block done)
//            z flags      @ u32[48+l]              (==2 when both dirs done)
//   1024     zbuf  [2][64][512] bf16 = 131072   (zbuf0 survives -> fc)
//   132096   Gx_g  [2][64][1024] bf16 = 262144  (dead after lstm)
//   66560    convWb overlay (554688) over zbuf1+Gx — written during the FC
//            dispatch (after lstm), read by convs/head. No race.
//   621248   arenaA (20,574,208): x4b / c3o / c2o / c1o / c0o
//   21195456 arenaB: p3/p2/p1/p0 @0; fcWb @2,097,152 (written PRE-lstm by
//            precvt — no overlap with whhq/swp/lstm state; dead after fc,
//            clobbered by p2); WhhQ i8 @11,534,336 + swp @14,155,776
//            (written pre-lstm, dead after lstm, clobbered by p0)
// LESSONS ENCODED:
//  - r3: per-step direct-global Gx reads cost ~800cy cross-XCD latency; LDS
//    bulk staging per 16 steps is required.
//  - r4/r6: merging precvt INTO the lstm grid costs ~+60us of memory-system
//    interference on the Phase-A/recurrence critical path regardless of
//    gating scheme; a serial ~15us pre-dispatch is cheaper.
//  - r5: spinner blocks must stay << resident capacity (dispatch order is
//    UNDEFINED across XCDs); here only 2 recurrence blocks ever spin.
//  - r7(this): __syncthreads drains vmcnt(0); per-STEP global z-stores put a
//    store-ack on every step. z goes to LDS; flush once per 16-step block.
// ---------------------------------------------------------------------------
#define ZBUF_OFF   1024
#define GX_OFF     132096
#define CONVW_OFF  66560
#define ARENA_A    621248
#define ARENA_B    21195456
#define WHHQ_BOFF  11534336
#define SWP_BOFF   14155776

// ---------------------------------------------------------------------------
// pre-lstm: Whh -> per-row-absmax int8 A-fragments + scales (bids 0..2559),
// fcW f32->bf16 (bids 2560..3839). Runs to completion before lstm (stream
// order) — nothing in lstm waits on weights.
// m = cell*4 + gate; weight row r = gate*256 + cell.
// ---------------------------------------------------------------------------
__global__ __launch_bounds__(256) void precvt(
    const float* __restrict__ Whh0, const float* __restrict__ WhhL,
    signed char* __restrict__ WhhQ, float* __restrict__ swp,
    const float* __restrict__ fcW, __bf16* __restrict__ fcWb)
{
    if (blockIdx.x >= 2560) {
        int f = ((blockIdx.x - 2560) * 256 + threadIdx.x) * 4;
        if (f < 1310720) {
            float4 v = *(const float4*)(fcW + f);
            g4u u;
            u.h[0] = (__bf16)v.x; u.h[1] = (__bf16)v.y;
            u.h[2] = (__bf16)v.z; u.h[3] = (__bf16)v.w;
            *(unsigned long long*)(fcWb + f) = u.q;
        }
        return;
    }
    const int g  = blockIdx.x * 4 + (threadIdx.x >> 6);   // 0..10239
    const int dl = g >> 10;
    const int r  = g & 1023;
    const int lane = threadIdx.x & 63;
    const float* src = (dl < 2 ? Whh0 + (size_t)dl * 262144
                               : WhhL + (size_t)(dl - 2) * 262144) + (size_t)r * 256;
    float4 v = *(const float4*)(src + lane * 4);
    float am = fmaxf(fmaxf(fabsf(v.x), fabsf(v.y)), fmaxf(fabsf(v.z), fabsf(v.w)));
    #pragma unroll
    for (int m = 1; m < 64; m <<= 1) am = fmaxf(am, __shfl_xor(am, m));
    const float inv = am > 0.f ? 127.f / am : 0.f;
    int q0 = __float2int_rn(v.x * inv), q1 = __float2int_rn(v.y * inv);
    int q2 = __float2int_rn(v.z * inv), q3 = __float2int_rn(v.w * inv);
    unsigned pk = (q0 & 255) | ((q1 & 255) << 8) | ((q2 & 255) << 16) | ((q3 & 255) << 24);
    const int gate = r >> 8, cell = r & 255;
    const int m  = cell * 4 + gate;
    const int lm = m & 15, mt = m >> 4;
    const int k  = lane * 4;
    const int kc = k >> 6, qd = (k >> 4) & 3, j = k & 15;
    size_t addr = ((((size_t)dl * 64 + mt) * 4 + kc) * 64 + (qd * 16 + lm)) * 16 + j;
    *(unsigned*)(WhhQ + addr) = pk;
    if (lane == 0) swp[(size_t)dl * 1024 + cell * 4 + gate] = am / 127.f;
}

// ---------------------------------------------------------------------------
// Fused LSTM, grid = 18 x 512 (pure — no precvt interference):
//  bid 0..15 : Phase-A WGs (dir=bid>>3, sub=bid&7): Gx = Wih@x + b, produced
//    in four 16-timestep blocks in consumer order, signalled per block.
//  bid 16,17 : recurrence WGs (dir=bid-16), one CU each (MFMA i8 matvec,
//    wf[8][4] in AGPRs). Gx staged per 16-step block to LDS (32 KB bulk).
//    z written to LDS zq per step; flushed to global ONCE per 16-step block
//    (per-step global stores put a vmcnt(0) store-ack drain on every step's
//    __syncthreads — ~200-500cy x 320 steps).
// ---------------------------------------------------------------------------
__global__ __launch_bounds__(512) __attribute__((amdgpu_waves_per_eu(2, 2)))
void lstm_fused(
    const float* __restrict__ audio,
    const float* __restrict__ Wih0,     // [2][1024][768] f32
    const float* __restrict__ WihL,     // [4][2][1024][512] f32
    const signed char* __restrict__ WhhQ,
    const float* __restrict__ swp,
    const float* __restrict__ b0, const float* __restrict__ bL,
    unsigned short* __restrict__ Gx_g,  // [2][64][1024] bf16 bits
    unsigned int* __restrict__ flags,
    unsigned short* __restrict__ zbuf)  // [2][64][512] bf16 bits
{
    const int bid = blockIdx.x;
    const int tid = threadIdx.x;
    const int wave = tid >> 6, lane = tid & 63, ln = lane & 15, quad = lane >> 4;

    __shared__ __align__(16) signed char    hq[2][256];
    __shared__ __align__(16) signed char    zq[4096];      // [16 t][256 cell] i8
    __shared__ __align__(16) unsigned short gx_l[16384];   // [16 t][1024] bf16 bits

    if (bid < 16) {
        // ---------------- Phase A ----------------
        const int dir = bid >> 3, sub = bid & 7;
        const int gmt = sub * 8 + wave;          // global m-tile 0..63
        const int m_a = gmt * 16 + ln;
        const int r_a = (m_a & 3) * 256 + (m_a >> 2);
        unsigned short* GxO = Gx_g + (size_t)dir * 65536;

        // ---- layer 0 (no wait; weights cached in regs) ----
        {
            const float* Wih_l = Wih0 + (size_t)dir * 786432;
            const float* b_l   = b0 + (size_t)dir * 1024;
            bf16x8 afr[24];
            #pragma unroll
            for (int kc = 0; kc < 24; ++kc)
                afr[kc] = cvt8(Wih_l + (size_t)r_a * 768 + kc * 32 + quad * 8);
            float bv[4];
            #pragma unroll
            for (int reg = 0; reg < 4; ++reg) {
                const int m_row = gmt * 16 + quad * 4 + reg;
                bv[reg] = b_l[(m_row & 3) * 256 + (m_row >> 2)];
            }
            for (int ii = 0; ii < 4; ++ii) {
                const int nt = dir ? 3 - ii : ii;
                const int t  = nt * 16 + ln;
                f32x4 acA = (f32x4){0.f, 0.f, 0.f, 0.f};
                f32x4 acB = (f32x4){0.f, 0.f, 0.f, 0.f};
                #pragma unroll
                for (int kc = 0; kc < 24; kc += 2) {
                    acA = mfma16(afr[kc],
                                 cvt8(audio + (size_t)t * 768 + kc * 32 + quad * 8), acA);
                    acB = mfma16(afr[kc + 1],
                                 cvt8(audio + (size_t)t * 768 + (kc + 1) * 32 + quad * 8), acB);
                }
                f32x4 acc = acA + acB;
                #pragma unroll
                for (int reg = 0; reg < 4; ++reg) {
                    const int m_row = gmt * 16 + quad * 4 + reg;
                    __bf16 v = (__bf16)(acc[reg] + bv[reg]);
                    GxO[(size_t)t * 1024 + m_row] = __builtin_bit_cast(unsigned short, v);
                }
                __syncthreads();
                if (tid == 0) { __threadfence(); signal_add(&flags[(0 * 2 + dir) * 4 + nt]); }
            }
        }

        // ---- layers 1-4: prefetch Wih fragment into regs, THEN wait ----
        for (int l = 1; l < 5; ++l) {
            const float* Wih_l = WihL + (size_t)((l - 1) * 2 + dir) * 524288;
            const float* b_l   = bL + (size_t)((l - 1) * 2 + dir) * 1024;
            bf16x8 afr[16];
            #pragma unroll
            for (int kc = 0; kc < 16; ++kc)
                afr[kc] = cvt8(Wih_l + (size_t)r_a * 512 + kc * 32 + quad * 8);
            float bv[4];
            #pragma unroll
            for (int reg = 0; reg < 4; ++reg) {
                const int m_row = gmt * 16 + quad * 4 + reg;
                bv[reg] = b_l[(m_row & 3) * 256 + (m_row >> 2)];
            }
            if (tid == 0) wait_eq<4>(&flags[48 + (l - 1)], 2u);
            __syncthreads();
            const __bf16* zp = (const __bf16*)(zbuf + (size_t)((l - 1) & 1) * 32768);

            for (int ii = 0; ii < 4; ++ii) {
                const int nt = dir ? 3 - ii : ii;
                const int t  = nt * 16 + ln;
                f32x4 acA = (f32x4){0.f, 0.f, 0.f, 0.f};
                f32x4 acB = (f32x4){0.f, 0.f, 0.f, 0.f};
                #pragma unroll
                for (int kc = 0; kc < 16; kc += 2) {
                    acA = mfma16(afr[kc],
                                 *(const bf16x8*)(zp + (size_t)t * 512 + kc * 32 + quad * 8), acA);
                    acB = mfma16(afr[kc + 1],
                                 *(const bf16x8*)(zp + (size_t)t * 512 + (kc + 1) * 32 + quad * 8), acB);
                }
                f32x4 acc = acA + acB;
                #pragma unroll
                for (int reg = 0; reg < 4; ++reg) {
                    const int m_row = gmt * 16 + quad * 4 + reg;
                    __bf16 v = (__bf16)(acc[reg] + bv[reg]);
                    GxO[(size_t)t * 1024 + m_row] = __builtin_bit_cast(unsigned short, v);
                }
                __syncthreads();
                if (tid == 0) { __threadfence(); signal_add(&flags[(l * 2 + dir) * 4 + nt]); }
            }
        }
    } else {
        // ---------------- recurrence (MFMA i8, LDS-staged Gx, LDS z) --------
        const int dir = bid - 16;
        const unsigned short* Gx_d = Gx_g + (size_t)dir * 65536;
        const bool owner = (ln < 8);
        const int cell = wave * 32 + ln * 4 + quad;   // valid when owner
        const int gcell = owner ? cell : 0;
        const i32x4 czero = (i32x4){0, 0, 0, 0};

        for (int l = 0; l < 5; ++l) {
            const int dl = l * 2 + dir;
            // register-resident int8 Whh (loads overlap the Phase-A wait)
            i32x4 wf[8][4];
            const i32x4* wb = (const i32x4*)(WhhQ + (size_t)dl * 262144);
            #pragma unroll
            for (int i = 0; i < 8; ++i)
                #pragma unroll
                for (int kc = 0; kc < 4; ++kc)
                    wf[i][kc] = wb[(size_t)(((wave * 8 + i) * 4 + kc)) * 64 + lane];
            float sc0 = 0.f, sc1 = 0.f, sc2 = 0.f, sc3 = 0.f;
            if (owner) {
                float4 s4 = *(const float4*)(swp + (size_t)dl * 1024 + cell * 4);
                const float f = 1.f / 127.f;
                sc0 = s4.x * f; sc1 = s4.y * f; sc2 = s4.z * f; sc3 = s4.w * f;
            }
            if (tid < 64) ((unsigned int*)hq[0])[tid] = 0;
            float cst = 0.f;
            unsigned short* zl = zbuf + (size_t)(l & 1) * 32768;
            const int gxbase = (l * 2 + dir) * 4;

            for (int blk = 0; blk < 4; ++blk) {
                const int nt = dir ? 3 - blk : blk;
                // wait for + stage this 16-t block of Gx (32 KB)
                if (tid == 0) wait_eq<1>(&flags[gxbase + nt], 8u);
                __syncthreads();
                {
                    const float4* src = (const float4*)(Gx_d + (size_t)nt * 16384);
                    float4* dst = (float4*)gx_l;
                    #pragma unroll
                    for (int i = 0; i < 4; ++i) dst[i * 512 + tid] = src[i * 512 + tid];
                }
                __syncthreads();

                for (int ss = 0; ss < 16; ++ss) {
                    const int s = blk * 16 + ss;
                    const int tl = dir ? 15 - ss : ss;          // t = nt*16 + tl
                    const int cur = s & 1, nxt = cur ^ 1;
                    // early, unconditional LDS read of this step's gate bias
                    g4u gx;
                    gx.q = *(const unsigned long long*)&gx_l[tl * 1024 + gcell * 4];
                    i32x4 acc[8];
                    {
                        i32x4 b0v = *(const i32x4*)&hq[cur][quad * 16];
                        #pragma unroll
                        for (int i = 0; i < 8; ++i) acc[i] = mfma_i8(wf[i][0], b0v, czero);
                    }
                    #pragma unroll
                    for (int kc = 1; kc < 4; ++kc) {
                        i32x4 b = *(const i32x4*)&hq[cur][kc * 64 + quad * 16];
                        #pragma unroll
                        for (int i = 0; i < 8; ++i) acc[i] = mfma_i8(wf[i][kc], b, acc[i]);
                    }
                    i32x4 a = acc[0];
                    #pragma unroll
                    for (int j = 1; j < 8; ++j) if (ln == j) a = acc[j];
                    if (owner) {
                        float gi = (float)a[0] * sc0 + (float)gx.h[0];
                        float gf = (float)a[1] * sc1 + (float)gx.h[1];
                        float gg = (float)a[2] * sc2 + (float)gx.h[2];
                        float go = (float)a[3] * sc3 + (float)gx.h[3];
                        cst = sigm(gf) * cst + sigm(gi) * tanh_(gg);
                        float h = sigm(go) * tanh_(cst);
                        int q = __float2int_rn(h * 127.f);
                        hq[nxt][cell] = (signed char)q;
                        zq[tl * 256 + cell] = (signed char)q;    // LDS, no vmcnt
                    }
                    __syncthreads();
                }
                // flush this block's 16 t-rows of z (i8 -> bf16) to global.
                // Store-ack drains once per block at the next staging barrier.
                #pragma unroll
                for (int i = 0; i < 2; ++i) {
                    const int d = i * 512 + tid;        // dword 0..1023
                    const int tf = d >> 4, cb = (d & 15) * 4;
                    unsigned u = ((const unsigned*)zq)[d];
                    g4u o;
                    #pragma unroll
                    for (int j = 0; j < 4; ++j) {
                        int bch = (int)(signed char)(u >> (8 * j));
                        o.h[j] = (__bf16)((float)bch * (1.f / 127.f));
                    }
                    *(unsigned long long*)(zl + (size_t)(nt * 16 + tf) * 512 + dir * 256 + cb) = o.q;
                }
            }
            // publish layer (threadfence orders the flush stores)
            if (tid == 0) { __threadfence(); signal_add(&flags[48 + l]); }
        }
    }
}

// ---------------------------------------------------------------------------
// fc (+ conv-weight conversion in spare blocks; runs after lstm so the
// zbuf1/Gx overlay region is dead): grid = 40 + 271.
// ---------------------------------------------------------------------------
__global__ __launch_bounds__(256) void fc_kernel(
    const __bf16* __restrict__ zb, const __bf16* __restrict__ W,
    const float* __restrict__ bb, __bf16* __restrict__ out,
    const float* __restrict__ c3W, const float* __restrict__ c2W,
    const float* __restrict__ c1W, const float* __restrict__ c0W,
    const float* __restrict__ hW, __bf16* __restrict__ convWb)
{
    const int tid = threadIdx.x;
    if (blockIdx.x >= 40) {
        int f = ((blockIdx.x - 40) * 256 + tid) * 4;
        if (f < 277344) {
            const float* src; int off;
            if (f < 147456)      { src = c3W; off = f; }
            else if (f < 221184) { src = c2W; off = f - 147456; }
            else if (f < 258048) { src = c1W; off = f - 221184; }
            else if (f < 276480) { src = c0W; off = f - 258048; }
            else                 { src = hW;  off = f - 276480; }
            float4 v = *(const float4*)(src + off);
            g4u u;
            u.h[0] = (__bf16)v.x; u.h[1] = (__bf16)v.y;
            u.h[2] = (__bf16)v.z; u.h[3] = (__bf16)v.w;
            *(unsigned long long*)(convWb + f) = u.q;
        }
        return;
    }
    const int wave = tid >> 6, lane = tid & 63, ln = lane & 15, quad = lane >> 4;
    const int nbase = blockIdx.x * 64;
    f32x4 acc[4];
    #pragma unroll
    for (int nt = 0; nt < 4; nt++) acc[nt] = (f32x4){0.f, 0.f, 0.f, 0.f};
    #pragma unroll 2
    for (int kc = 0; kc < 16; kc++) {
        const int k0 = kc * 32 + quad * 8;
        bf16x8 a = *(const bf16x8*)(zb + (size_t)(wave * 16 + ln) * 512 + k0);
        #pragma unroll
        for (int nt = 0; nt < 4; nt++) {
            bf16x8 b = *(const bf16x8*)(W + (size_t)(nbase + nt * 16 + ln) * 512 + k0);
            acc[nt] = mfma16(a, b, acc[nt]);
        }
    }
    #pragma unroll
    for (int nt = 0; nt < 4; nt++) {
        const int n = nbase + nt * 16 + ln;
        const float bv = bb[n];
        #pragma unroll
        for (int reg = 0; reg < 4; reg++) {
            const int t = wave * 16 + quad * 4 + reg;
            out[(size_t)((n >> 7) * 64 + t) * 128 + (n & 127)] = (__bf16)(acc[nt][reg] + bv);
        }
    }
}

// ---------------------------------------------------------------------------
// pool: out[r][t][:] = sum_{s=0..2} vals[3r+s] * in[cols[3r+s]][t][:]
// ---------------------------------------------------------------------------
template <int C>
__global__ __launch_bounds__(256) void pool_kernel(
    const __bf16* __restrict__ in, __bf16* __restrict__ out,
    const int* __restrict__ cols, const float* __restrict__ vals, int V)
{
    const int P = 64 * C / 8;
    const int gid = blockIdx.x * 256 + threadIdx.x;
    if (gid >= V * P) return;
    const int r = gid / P;
    const int rem = gid - r * P;
    float acc[8] = {0.f, 0.f, 0.f, 0.f, 0.f, 0.f, 0.f, 0.f};
    #pragma unroll
    for (int s = 0; s < 3; s++) {
        const int col = cols[3 * r + s];
        const float vv = vals[3 * r + s];
        bf16x8 x = *(const bf16x8*)(in + (size_t)col * 64 * C + rem * 8);
        #pragma unroll
        for (int e = 0; e < 8; e++) acc[e] += vv * (float)x[e];
    }
    bf16x8 ov;
    #pragma unroll
    for (int e = 0; e < 8; e++) ov[e] = (__bf16)acc[e];
    *(bf16x8*)(out + (size_t)r * 64 * C + rem * 8) = ov;
}

// ---------------------------------------------------------------------------
// spiral conv + ELU: one WAVE per (vertex, 16-t chunk). grid = (V, 4) x 64.
// ---------------------------------------------------------------------------
template <int CIN, int COUT>
__global__ __launch_bounds__(64) void conv_kernel(
    const __bf16* __restrict__ in, __bf16* __restrict__ out,
    const int* __restrict__ idx, const __bf16* __restrict__ W,
    const float* __restrict__ bias)
{
    constexpr int K = 9 * CIN;
    constexpr int NT = COUT / 16;
    constexpr int NKC = K / 32;
    const int v = blockIdx.x;
    const int lane = threadIdx.x, ln = lane & 15, quad = lane >> 4;
    const int t0 = blockIdx.y * 16;
    __shared__ int sIdx[9];
    if (lane < 9) sIdx[lane] = idx[v * 9 + lane];
    __syncthreads();
    f32x4 acc[NT];
    #pragma unroll
    for (int nt = 0; nt < NT; nt++) acc[nt] = (f32x4){0.f, 0.f, 0.f, 0.f};
    const int tt = t0 + ln;
    for (int kc = 0; kc < NKC; kc++) {
        const int k0 = kc * 32;
        const int l = k0 / CIN;
        const int c = (k0 & (CIN - 1)) + quad * 8;
        const int row = sIdx[l];
        bf16x8 a = *(const bf16x8*)(in + ((size_t)row * 64 + tt) * CIN + c);
        #pragma unroll
        for (int nt = 0; nt < NT; nt++) {
            bf16x8 b = *(const bf16x8*)(W + (size_t)(nt * 16 + ln) * K + k0 + quad * 8);
            acc[nt] = mfma16(a, b, acc[nt]);
        }
    }
    #pragma unroll
    for (int nt = 0; nt < NT; nt++) {
        const int n = nt * 16 + ln;
        const float bv = bias[n];
        #pragma unroll
        for (int reg = 0; reg < 4; reg++) {
            const int t = t0 + quad * 4 + reg;
            float val = acc[nt][reg] + bv;
            val = val > 0.f ? val : (__expf(val) - 1.f);   // ELU
            out[((size_t)v * 64 + t) * COUT + n] = (__bf16)val;
        }
    }
}

// ---------------------------------------------------------------------------
// head: spiral conv to 3 ch + actor offset -> [64][5023][3] f32.
// One wave per (vertex, 16-t chunk): grid = (5023, 4) x 64.
// ---------------------------------------------------------------------------
__global__ __launch_bounds__(64) void head_kernel(
    const __bf16* __restrict__ in, float* __restrict__ out,
    const int* __restrict__ idx, const __bf16* __restrict__ W,
    const float* __restrict__ bias, const float* __restrict__ actor)
{
    const int v = blockIdx.x;
    const int lane = threadIdx.x, ln = lane & 15, quad = lane >> 4;
    const int t0 = blockIdx.y * 16;
    __shared__ int sIdx[9];
    if (lane < 9) sIdx[lane] = idx[v * 9 + lane];
    __syncthreads();
    f32x4 acc = (f32x4){0.f, 0.f, 0.f, 0.f};
    const int tt = t0 + ln;
    const int rown = ln < 3 ? ln : 0;
    #pragma unroll
    for (int kc = 0; kc < 9; kc++) {
        const int row = sIdx[kc];
        bf16x8 a = *(const bf16x8*)(in + ((size_t)row * 64 + tt) * 32 + quad * 8);
        bf16x8 b = *(const bf16x8*)(W + (size_t)rown * 288 + kc * 32 + quad * 8);
        acc = mfma16(a, b, acc);
    }
    if (ln < 3) {
        const float bv = bias[ln];
        const float av = actor[v * 3 + ln];
        #pragma unroll
        for (int reg = 0; reg < 4; reg++) {
            const int t = t0 + quad * 4 + reg;
            out[((size_t)t * 5023 + v) * 3 + ln] = acc[reg] + bv + av;
        }
    }
}

extern "C" void kernel_launch(void* const* d_in, const int* in_sizes, int n_in,
                              void* d_out, int out_size, void* d_ws, size_t ws_size,
                              hipStream_t stream) {
    const float* audio = (const float*)d_in[0];
    const float* actor = (const float*)d_in[1];
    const float* Wih0  = (const float*)d_in[2];
    const float* Whh0  = (const float*)d_in[3];
    const float* b0    = (const float*)d_in[4];
    const float* WihL  = (const float*)d_in[5];
    const float* WhhL  = (const float*)d_in[6];
    const float* bLs   = (const float*)d_in[7];
    const float* fcW   = (const float*)d_in[8];
    const float* fcb   = (const float*)d_in[9];
    const float* c3W = (const float*)d_in[10]; const float* c3b = (const float*)d_in[11];
    const float* c2W = (const float*)d_in[12]; const float* c2b = (const float*)d_in[13];
    const float* c1W = (const float*)d_in[14]; const float* c1b = (const float*)d_in[15];
    const float* c0W = (const float*)d_in[16]; const float* c0b = (const float*)d_in[17];
    const float* hW  = (const float*)d_in[18]; const float* hb  = (const float*)d_in[19];
    const int* idx0 = (const int*)d_in[20];
    const int* idx1 = (const int*)d_in[21];
    const int* idx2 = (const int*)d_in[22];
    const int* idx3 = (const int*)d_in[23];
    const int* cols0 = (const int*)d_in[25]; const float* vals0 = (const float*)d_in[26];
    const int* cols1 = (const int*)d_in[28]; const float* vals1 = (const float*)d_in[29];
    const int* cols2 = (const int*)d_in[31]; const float* vals2 = (const float*)d_in[32];
    const int* cols3 = (const int*)d_in[34]; const float* vals3 = (const float*)d_in[35];

    char* ws = (char*)d_ws;
    unsigned int*   flags = (unsigned int*)ws;
    unsigned short* zbuf  = (unsigned short*)(ws + ZBUF_OFF);
    unsigned short* GxG   = (unsigned short*)(ws + GX_OFF);
    __bf16*         convWb = (__bf16*)(ws + CONVW_OFF);
    char* arenaA = ws + ARENA_A;
    char* arenaB = ws + ARENA_B;

    signed char* whhq = (signed char*)(arenaB + WHHQ_BOFF);   // dead after lstm
    float*       swp  = (float*)(arenaB + SWP_BOFF);          // dead after lstm
    __bf16*      fcWb = (__bf16*)(arenaB + 2097152);          // dead after fc

    __bf16* x4b = (__bf16*)arenaA;   // [20][64][128]
    __bf16* p3  = (__bf16*)arenaB;   // [79][64][128]
    __bf16* c3o = (__bf16*)arenaA;   // [79][64][128]
    __bf16* p2  = (__bf16*)arenaB;   // [314][64][128]
    __bf16* c2o = (__bf16*)arenaA;   // [314][64][64]
    __bf16* p1  = (__bf16*)arenaB;   // [1256][64][64]
    __bf16* c1o = (__bf16*)arenaA;   // [1256][64][64]
    __bf16* p0  = (__bf16*)arenaB;   // [5023][64][64]
    __bf16* c0o = (__bf16*)arenaA;   // [5023][64][32]

    (void)hipMemsetAsync(ws, 0, 1024, stream);   // flags

    precvt<<<3840, 256, 0, stream>>>(Whh0, WhhL, whhq, swp, fcW, fcWb);

    lstm_fused<<<18, 512, 0, stream>>>(audio, Wih0, WihL, whhq, swp, b0, bLs,
                                       GxG, flags, zbuf);

    fc_kernel<<<40 + 271, 256, 0, stream>>>((const __bf16*)zbuf, fcWb, fcb, x4b,
                                            c3W, c2W, c1W, c0W, hW, convWb);

    { int n = 79 * 64 * 128 / 8;
      pool_kernel<128><<<(n + 255) / 256, 256, 0, stream>>>(x4b, p3, cols3, vals3, 79);
      conv_kernel<128, 128><<<dim3(79, 4), 64, 0, stream>>>(p3, c3o, idx3, convWb + 0, c3b); }
    { int n = 314 * 64 * 128 / 8;
      pool_kernel<128><<<(n + 255) / 256, 256, 0, stream>>>(c3o, p2, cols2, vals2, 314);
      conv_kernel<128, 64><<<dim3(314, 4), 64, 0, stream>>>(p2, c2o, idx2, convWb + 147456, c2b); }
    { int n = 1256 * 64 * 64 / 8;
      pool_kernel<64><<<(n + 255) / 256, 256, 0, stream>>>(c2o, p1, cols1, vals1, 1256);
      conv_kernel<64, 64><<<dim3(1256, 4), 64, 0, stream>>>(p1, c1o, idx1, convWb + 221184, c1b); }
    { int n = 5023 * 64 * 64 / 8;
      pool_kernel<64><<<(n + 255) / 256, 256, 0, stream>>>(c1o, p0, cols0, vals0, 5023);
      conv_kernel<64, 32><<<dim3(5023, 4), 64, 0, stream>>>(p0, c0o, idx0, convWb + 258048, c0b); }

    head_kernel<<<dim3(5023, 4), 64, 0, stream>>>(c0o, (float*)d_out, idx0,
                                                  convWb + 276480, hb, actor);
}